// Round 1
// baseline (442.413 us; speedup 1.0000x reference)
//
#include <hip/hip_runtime.h>
#include <cstdint>
#include <cstddef>

// ---------------------------------------------------------------------------
// GCN: out = relu(BN2(A' relu(BN1(A' BN0(X) W1)) W2)) Wf + bf
// A' = D^-1/2 (A+I) D^-1/2, applied via per-call CSR (sorted by dst).
// Conv biases b1,b2 cancel inside the following BatchNorm (mean shift) and
// are skipped. BN affine (a,b per column) is fused into GEMM X-staging.
// ---------------------------------------------------------------------------

// ---- column stats: st[0..127]=sum, st[128..255]=sum of squares ------------
__global__ __launch_bounds__(256) void k_colstats(const float* __restrict__ X,
                                                  int n, float* __restrict__ st) {
    int col  = threadIdx.x & 127;
    int half = threadIdx.x >> 7;   // 0/1
    float s = 0.f, ss = 0.f;
    for (int r = blockIdx.x * 2 + half; r < n; r += gridDim.x * 2) {
        float v = X[(size_t)r * 128 + col];
        s += v; ss += v * v;
    }
    atomicAdd(&st[col], s);
    atomicAdd(&st[128 + col], ss);
}

__global__ void k_bnparams(const float* __restrict__ st, const float* __restrict__ g,
                           const float* __restrict__ be, float invn,
                           float* __restrict__ a, float* __restrict__ b) {
    int c = threadIdx.x;           // 128 threads
    float mu   = st[c] * invn;
    float var  = st[128 + c] * invn - mu * mu;
    float rstd = rsqrtf(var + 1e-5f);
    float av   = g[c] * rstd;
    a[c] = av;
    b[c] = be[c] - mu * av;
}

// ---- CSR build ------------------------------------------------------------
__global__ __launch_bounds__(256) void k_count(const int* __restrict__ dst, int e,
                                               int* __restrict__ cnt) {
    int i = blockIdx.x * 256 + threadIdx.x;
    if (i < e) atomicAdd(&cnt[dst[i]], 1);
}

__global__ __launch_bounds__(1024) void k_scanA(const int* __restrict__ cnt, int n,
                                                int* __restrict__ rs, int* __restrict__ bsum) {
    __shared__ int tmp[1024];
    int t = threadIdx.x;
    int i = blockIdx.x * 1024 + t;
    int v = (i < n) ? cnt[i] : 0;
    tmp[t] = v;
    __syncthreads();
    for (int off = 1; off < 1024; off <<= 1) {
        int x = (t >= off) ? tmp[t - off] : 0;
        __syncthreads();
        tmp[t] += x;
        __syncthreads();
    }
    if (i < n) rs[i] = tmp[t] - v;                 // exclusive within chunk
    if (t == 1023) bsum[blockIdx.x] = tmp[t];      // chunk total
}

__global__ void k_scanB(const int* __restrict__ bsum, int nb,
                        int* __restrict__ boff, int* __restrict__ rs, int n) {
    int run = 0;
    for (int b = 0; b < nb; ++b) { boff[b] = run; run += bsum[b]; }
    rs[n] = run;
}

__global__ __launch_bounds__(256) void k_scanC(int* __restrict__ rs,
                                               const int* __restrict__ boff, int n) {
    int i = blockIdx.x * 256 + threadIdx.x;
    if (i < n) rs[i] += boff[i >> 10];
}

__global__ __launch_bounds__(256) void k_dinv(const int* __restrict__ cnt, int n,
                                              float* __restrict__ dinv) {
    int i = blockIdx.x * 256 + threadIdx.x;
    if (i < n) dinv[i] = rsqrtf((float)(cnt[i] + 1));   // +1 self loop
}

__global__ __launch_bounds__(256) void k_fill(const int* __restrict__ src,
                                              const int* __restrict__ dst, int e,
                                              const int* __restrict__ rs,
                                              int* __restrict__ cursor,
                                              const float* __restrict__ dinv,
                                              int* __restrict__ esrc,
                                              float* __restrict__ enorm) {
    int i = blockIdx.x * 256 + threadIdx.x;
    if (i < e) {
        int d = dst[i], s = src[i];
        int p = rs[d] + atomicAdd(&cursor[d], 1);
        esrc[p]  = s;
        enorm[p] = dinv[s] * dinv[d];
    }
}

// ---- GEMM: H[n][128] = f(X) @ W,  f = affine(+relu) fused on X load -------
// Tile: 64 rows x 64 cols (blockIdx.y = col half). W staged in two K-halves.
__global__ __launch_bounds__(256) void k_gemm128(const float* __restrict__ X,
                                                 const float* __restrict__ W,
                                                 const float* __restrict__ a,
                                                 const float* __restrict__ b,
                                                 int relu,
                                                 float* __restrict__ H, int n) {
    __shared__ float wl[64 * 64];     // 16 KB (one K-half of one col-block)
    __shared__ float xl[64 * 132];    // 33.8 KB (padded stride 132)
    const int tid = threadIdx.x;
    const int cb  = blockIdx.y;       // 0/1: which 64 output cols
    const int row0 = blockIdx.x * 64;

    // stage X rows with BN affine (+relu)
    {
        for (int i = tid; i < 64 * 32; i += 256) {
            int r = i >> 5, c4 = i & 31;
            int gr = row0 + r;
            float4 v = make_float4(0.f, 0.f, 0.f, 0.f);
            if (gr < n) v = ((const float4*)(X + (size_t)gr * 128))[c4];
            float4 a4 = ((const float4*)a)[c4];
            float4 b4 = ((const float4*)b)[c4];
            v.x = fmaf(v.x, a4.x, b4.x);
            v.y = fmaf(v.y, a4.y, b4.y);
            v.z = fmaf(v.z, a4.z, b4.z);
            v.w = fmaf(v.w, a4.w, b4.w);
            if (relu) {
                v.x = fmaxf(v.x, 0.f); v.y = fmaxf(v.y, 0.f);
                v.z = fmaxf(v.z, 0.f); v.w = fmaxf(v.w, 0.f);
            }
            *(float4*)&xl[r * 132 + (c4 << 2)] = v;
        }
    }

    const int cg = tid & 15;   // 16 col groups x 4 cols
    const int rg = tid >> 4;   // 16 row groups x 4 rows
    float acc[4][4] = {{0.f}};

    for (int h = 0; h < 2; ++h) {
        __syncthreads();   // x staged (h=0) / previous wl consumed (h=1)
        {
            float4* wl4 = (float4*)wl;
            const float4* W4 = (const float4*)W;
            for (int i = tid; i < 64 * 16; i += 256) {
                int r = i >> 4, c4 = i & 15;
                wl4[i] = W4[(size_t)(h * 64 + r) * 32 + cb * 16 + c4];
            }
        }
        __syncthreads();
        for (int c = 0; c < 64; c += 4) {
            float4 xv[4];
            #pragma unroll
            for (int i = 0; i < 4; ++i)
                xv[i] = *(const float4*)&xl[(rg * 4 + i) * 132 + h * 64 + c];
            #pragma unroll
            for (int cc = 0; cc < 4; ++cc) {
                float4 wv = *(const float4*)&wl[(c + cc) * 64 + cg * 4];
                #pragma unroll
                for (int i = 0; i < 4; ++i) {
                    float xs = (&xv[i].x)[cc];
                    acc[i][0] = fmaf(xs, wv.x, acc[i][0]);
                    acc[i][1] = fmaf(xs, wv.y, acc[i][1]);
                    acc[i][2] = fmaf(xs, wv.z, acc[i][2]);
                    acc[i][3] = fmaf(xs, wv.w, acc[i][3]);
                }
            }
        }
    }

    const int colbase = cb * 64 + cg * 4;
    #pragma unroll
    for (int i = 0; i < 4; ++i) {
        int gr = row0 + rg * 4 + i;
        if (gr < n) {
            float4 o = make_float4(acc[i][0], acc[i][1], acc[i][2], acc[i][3]);
            *(float4*)&H[(size_t)gr * 128 + colbase] = o;
        }
    }
}

// ---- aggregation: AGG[n] = self_norm[n]*H[n] + sum_{e->n} norm_e * H[src_e]
__global__ __launch_bounds__(256) void k_aggregate(const float* __restrict__ H,
                                                   const int* __restrict__ rs,
                                                   const int* __restrict__ esrc,
                                                   const float* __restrict__ enorm,
                                                   const float* __restrict__ dinv,
                                                   float* __restrict__ AGG, int n) {
    int wid  = (blockIdx.x * 256 + threadIdx.x) >> 6;   // one wave per node
    int lane = threadIdx.x & 63;
    if (wid >= n) return;
    float sn = dinv[wid]; sn = sn * sn;
    float2 acc = ((const float2*)(H + (size_t)wid * 128))[lane];
    acc.x *= sn; acc.y *= sn;
    int e1 = rs[wid + 1];
    for (int i = rs[wid]; i < e1; ++i) {
        int   s = esrc[i];
        float w = enorm[i];
        float2 v = ((const float2*)(H + (size_t)s * 128))[lane];
        acc.x = fmaf(w, v.x, acc.x);
        acc.y = fmaf(w, v.y, acc.y);
    }
    ((float2*)(AGG + (size_t)wid * 128))[lane] = acc;
}

// ---- final projection: OUT = relu(a*X+b) @ Wf + bf  (128 -> 40) -----------
__global__ __launch_bounds__(256) void k_gemm_out(const float* __restrict__ X,
                                                  const float* __restrict__ Wf,
                                                  const float* __restrict__ bfv,
                                                  const float* __restrict__ a,
                                                  const float* __restrict__ b,
                                                  float* __restrict__ OUT, int n) {
    __shared__ float xl[32 * 132];    // 16.9 KB
    __shared__ float wt[40 * 132];    // 21.1 KB, transposed Wf: wt[j][c]
    const int tid = threadIdx.x;

    for (int i = tid; i < 128 * 40; i += 256) {
        int c = i / 40;
        int j = i - c * 40;
        wt[j * 132 + c] = Wf[i];
    }
    const int row0 = blockIdx.x * 32;
    for (int i = tid; i < 32 * 32; i += 256) {
        int r = i >> 5, c4 = i & 31;
        int gr = row0 + r;
        float4 v = make_float4(0.f, 0.f, 0.f, 0.f);
        if (gr < n) v = ((const float4*)(X + (size_t)gr * 128))[c4];
        float4 a4 = ((const float4*)a)[c4];
        float4 b4 = ((const float4*)b)[c4];
        v.x = fmaxf(fmaf(v.x, a4.x, b4.x), 0.f);
        v.y = fmaxf(fmaf(v.y, a4.y, b4.y), 0.f);
        v.z = fmaxf(fmaf(v.z, a4.z, b4.z), 0.f);
        v.w = fmaxf(fmaf(v.w, a4.w, b4.w), 0.f);
        *(float4*)&xl[r * 132 + (c4 << 2)] = v;
    }
    __syncthreads();

    const int rg = tid >> 3;   // 32 rows
    const int cg = tid & 7;    // 8 groups x 5 cols
    const int j0 = cg * 5;
    float acc[5] = {0.f, 0.f, 0.f, 0.f, 0.f};
    for (int c = 0; c < 128; c += 4) {
        float4 xv = *(const float4*)&xl[rg * 132 + c];
        #pragma unroll
        for (int j = 0; j < 5; ++j) {
            float4 wv = *(const float4*)&wt[(j0 + j) * 132 + c];
            acc[j] = fmaf(xv.x, wv.x, acc[j]);
            acc[j] = fmaf(xv.y, wv.y, acc[j]);
            acc[j] = fmaf(xv.z, wv.z, acc[j]);
            acc[j] = fmaf(xv.w, wv.w, acc[j]);
        }
    }
    int gr = row0 + rg;
    if (gr < n) {
        #pragma unroll
        for (int j = 0; j < 5; ++j)
            OUT[(size_t)gr * 40 + j0 + j] = acc[j] + bfv[j0 + j];
    }
}

// ---------------------------------------------------------------------------
extern "C" void kernel_launch(void* const* d_in, const int* in_sizes, int n_in,
                              void* d_out, int out_size, void* d_ws, size_t ws_size,
                              hipStream_t stream) {
    const float* X0      = (const float*)d_in[0];
    const int*   edgesrc = (const int*)d_in[1];
    const int*   edgedst = (const int*)d_in[2];
    const float* bn0g = (const float*)d_in[3];
    const float* bn0b = (const float*)d_in[4];
    const float* W1   = (const float*)d_in[5];
    // d_in[6] = b1: cancels in BN1
    const float* bn1g = (const float*)d_in[7];
    const float* bn1b = (const float*)d_in[8];
    const float* W2   = (const float*)d_in[9];
    // d_in[10] = b2: cancels in BN2
    const float* bn2g = (const float*)d_in[11];
    const float* bn2b = (const float*)d_in[12];
    const float* Wf   = (const float*)d_in[13];
    const float* bfv  = (const float*)d_in[14];

    const int n = in_sizes[0] / 128;
    const int e = in_sizes[1];
    float* OUT = (float*)d_out;

    // workspace layout (floats/ints), ~57 MB total
    float* H     = (float*)d_ws;                 // n*128
    float* AGG   = H + (size_t)n * 128;          // n*128
    float* dinv  = AGG + (size_t)n * 128;        // n
    float* enorm = dinv + n;                     // e
    int*   esrc  = (int*)(enorm + e);            // e
    int*   cnt   = esrc + e;                     // n
    int*   rs    = cnt + n;                      // n+1
    int*   cursor= rs + n + 1;                   // n
    int*   bsum  = cursor + n;                   // 64
    int*   boff  = bsum + 64;                    // 64
    float* stats = (float*)(boff + 64);          // 3*256
    float* a0 = stats + 768; float* b0 = a0 + 128;
    float* a1 = b0 + 128;    float* b1 = a1 + 128;
    float* a2 = b1 + 128;    float* b2 = a2 + 128;

    hipMemsetAsync(cnt,    0, (size_t)n * sizeof(int), stream);
    hipMemsetAsync(cursor, 0, (size_t)n * sizeof(int), stream);
    hipMemsetAsync(stats,  0, 768 * sizeof(float), stream);

    const float invn = 1.f / (float)n;
    const int nb = (n + 1023) / 1024;

    // CSR build
    k_count<<<(e + 255) / 256, 256, 0, stream>>>(edgedst, e, cnt);
    k_scanA<<<nb, 1024, 0, stream>>>(cnt, n, rs, bsum);
    k_scanB<<<1, 1, 0, stream>>>(bsum, nb, boff, rs, n);
    k_scanC<<<(n + 255) / 256, 256, 0, stream>>>(rs, boff, n);
    k_dinv<<<(n + 255) / 256, 256, 0, stream>>>(cnt, n, dinv);
    k_fill<<<(e + 255) / 256, 256, 0, stream>>>(edgesrc, edgedst, e, rs, cursor,
                                                dinv, esrc, enorm);

    dim3 g1((n + 63) / 64, 2);
    int aggBlocks = (int)(((size_t)n * 64 + 255) / 256);

    // layer 1
    k_colstats<<<256, 256, 0, stream>>>(X0, n, stats);
    k_bnparams<<<1, 128, 0, stream>>>(stats, bn0g, bn0b, invn, a0, b0);
    k_gemm128<<<g1, 256, 0, stream>>>(X0, W1, a0, b0, 0, H, n);
    k_aggregate<<<aggBlocks, 256, 0, stream>>>(H, rs, esrc, enorm, dinv, AGG, n);

    // layer 2
    k_colstats<<<256, 256, 0, stream>>>(AGG, n, stats + 256);
    k_bnparams<<<1, 128, 0, stream>>>(stats + 256, bn1g, bn1b, invn, a1, b1);
    k_gemm128<<<g1, 256, 0, stream>>>(AGG, W2, a1, b1, 1, H, n);
    k_aggregate<<<aggBlocks, 256, 0, stream>>>(H, rs, esrc, enorm, dinv, AGG, n);

    // head
    k_colstats<<<256, 256, 0, stream>>>(AGG, n, stats + 512);
    k_bnparams<<<1, 128, 0, stream>>>(stats + 512, bn2g, bn2b, invn, a2, b2);
    k_gemm_out<<<(n + 31) / 32, 256, 0, stream>>>(AGG, Wf, bfv, a2, b2, OUT, n);
}

// Round 2
// 417.058 us; speedup vs baseline: 1.0608x; 1.0608x over previous
//
#include <hip/hip_runtime.h>
#include <cstdint>
#include <cstddef>

// ---------------------------------------------------------------------------
// GCN: out = relu(BN2(A' relu(BN1(A' BN0(X) W1)) W2)) Wf + bf
// A' = D^-1/2 (A+I) D^-1/2 via per-call CSR (sorted by dst).
// Conv biases b1,b2 cancel inside the following BatchNorm and are skipped.
// BN affine (a,b per column) is fused into GEMM X-staging.
// ---------------------------------------------------------------------------

// ---- column stats + fused BN-param finalize (last block) ------------------
// st[0..127]=sum, st[128..255]=sumsq. done = per-layer counter (zeroed).
__global__ __launch_bounds__(256) void k_colstats(const float* __restrict__ X,
                                                  int n, float* __restrict__ st,
                                                  int* __restrict__ done,
                                                  const float* __restrict__ g,
                                                  const float* __restrict__ be,
                                                  float invn,
                                                  float* __restrict__ a,
                                                  float* __restrict__ b,
                                                  int nblocks) {
    int col  = threadIdx.x & 127;
    int half = threadIdx.x >> 7;   // 0/1
    float s = 0.f, ss = 0.f;
    for (int r = blockIdx.x * 2 + half; r < n; r += gridDim.x * 2) {
        float v = X[(size_t)r * 128 + col];
        s += v; ss += v * v;
    }
    atomicAdd(&st[col], s);
    atomicAdd(&st[128 + col], ss);
    __threadfence();
    __shared__ int lastflag;
    if (threadIdx.x == 0)
        lastflag = (atomicAdd(done, 1) == nblocks - 1) ? 1 : 0;
    __syncthreads();
    if (lastflag && threadIdx.x < 128) {
        int c = threadIdx.x;
        float su = atomicAdd(&st[c], 0.f);        // coherent read
        float sq = atomicAdd(&st[128 + c], 0.f);
        float mu   = su * invn;
        float var  = sq * invn - mu * mu;
        float av   = g[c] * rsqrtf(var + 1e-5f);
        a[c] = av;
        b[c] = be[c] - mu * av;
    }
}

// ---- CSR build ------------------------------------------------------------
__global__ __launch_bounds__(256) void k_count(const int* __restrict__ dst, int e,
                                               int* __restrict__ cnt) {
    int i = blockIdx.x * 256 + threadIdx.x;
    if (i < e) atomicAdd(&cnt[dst[i]], 1);
}

__global__ __launch_bounds__(1024) void k_scanA(const int* __restrict__ cnt, int n,
                                                int* __restrict__ rs, int* __restrict__ bsum) {
    __shared__ int tmp[1024];
    int t = threadIdx.x;
    int i = blockIdx.x * 1024 + t;
    int v = (i < n) ? cnt[i] : 0;
    tmp[t] = v;
    __syncthreads();
    for (int off = 1; off < 1024; off <<= 1) {
        int x = (t >= off) ? tmp[t - off] : 0;
        __syncthreads();
        tmp[t] += x;
        __syncthreads();
    }
    if (i < n) rs[i] = tmp[t] - v;                 // exclusive within chunk
    if (t == 1023) bsum[blockIdx.x] = tmp[t];      // chunk total
}

// scanC: add chunk base (serial sum of bsum, per-block), dinv, rs[n]=e
__global__ __launch_bounds__(256) void k_scanC(int* __restrict__ rs,
                                               const int* __restrict__ bsum,
                                               const int* __restrict__ cnt,
                                               float* __restrict__ dinv,
                                               int n, int e) {
    __shared__ int base;
    int chunk = (int)(blockIdx.x >> 2);   // 4 blocks of 256 per 1024-chunk
    if (threadIdx.x == 0) {
        int s = 0;
        for (int c = 0; c < chunk; ++c) s += bsum[c];
        base = s;
    }
    __syncthreads();
    int i = blockIdx.x * 256 + threadIdx.x;
    if (i < n) {
        rs[i] += base;
        dinv[i] = rsqrtf((float)(cnt[i] + 1));   // +1 self loop
    }
    if (blockIdx.x == 0 && threadIdx.x == 0) rs[n] = e;
}

// fill: one packed 8B scatter per edge: (src, norm)
__global__ __launch_bounds__(256) void k_fill(const int* __restrict__ src,
                                              const int* __restrict__ dst, int e,
                                              const int* __restrict__ rs,
                                              int* __restrict__ cursor,
                                              const float* __restrict__ dinv,
                                              int2* __restrict__ ep) {
    int i = blockIdx.x * 256 + threadIdx.x;
    if (i < e) {
        int d = dst[i], s = src[i];
        int p = rs[d] + atomicAdd(&cursor[d], 1);
        float nm = dinv[s] * dinv[d];
        ep[p] = make_int2(s, __float_as_int(nm));
    }
}

// ---- GEMM: H[n][128] = f(X) @ W,  f = affine(+relu) fused on X load -------
__global__ __launch_bounds__(256) void k_gemm128(const float* __restrict__ X,
                                                 const float* __restrict__ W,
                                                 const float* __restrict__ a,
                                                 const float* __restrict__ b,
                                                 int relu,
                                                 float* __restrict__ H, int n) {
    __shared__ float wl[64 * 64];     // 16 KB (one K-half of one col-block)
    __shared__ float xl[64 * 132];    // 33.8 KB (padded stride 132)
    const int tid = threadIdx.x;
    const int cb  = blockIdx.y;       // 0/1: which 64 output cols
    const int row0 = blockIdx.x * 64;

    for (int i = tid; i < 64 * 32; i += 256) {
        int r = i >> 5, c4 = i & 31;
        int gr = row0 + r;
        float4 v = make_float4(0.f, 0.f, 0.f, 0.f);
        if (gr < n) v = ((const float4*)(X + (size_t)gr * 128))[c4];
        float4 a4 = ((const float4*)a)[c4];
        float4 b4 = ((const float4*)b)[c4];
        v.x = fmaf(v.x, a4.x, b4.x);
        v.y = fmaf(v.y, a4.y, b4.y);
        v.z = fmaf(v.z, a4.z, b4.z);
        v.w = fmaf(v.w, a4.w, b4.w);
        if (relu) {
            v.x = fmaxf(v.x, 0.f); v.y = fmaxf(v.y, 0.f);
            v.z = fmaxf(v.z, 0.f); v.w = fmaxf(v.w, 0.f);
        }
        *(float4*)&xl[r * 132 + (c4 << 2)] = v;
    }

    const int cg = tid & 15;   // 16 col groups x 4 cols
    const int rg = tid >> 4;   // 16 row groups x 4 rows
    float acc[4][4] = {{0.f}};

    for (int h = 0; h < 2; ++h) {
        __syncthreads();
        {
            float4* wl4 = (float4*)wl;
            const float4* W4 = (const float4*)W;
            for (int i = tid; i < 64 * 16; i += 256) {
                int r = i >> 4, c4 = i & 15;
                wl4[i] = W4[(size_t)(h * 64 + r) * 32 + cb * 16 + c4];
            }
        }
        __syncthreads();
        for (int c = 0; c < 64; c += 4) {
            float4 xv[4];
            #pragma unroll
            for (int i = 0; i < 4; ++i)
                xv[i] = *(const float4*)&xl[(rg * 4 + i) * 132 + h * 64 + c];
            #pragma unroll
            for (int cc = 0; cc < 4; ++cc) {
                float4 wv = *(const float4*)&wl[(c + cc) * 64 + cg * 4];
                #pragma unroll
                for (int i = 0; i < 4; ++i) {
                    float xs = (&xv[i].x)[cc];
                    acc[i][0] = fmaf(xs, wv.x, acc[i][0]);
                    acc[i][1] = fmaf(xs, wv.y, acc[i][1]);
                    acc[i][2] = fmaf(xs, wv.z, acc[i][2]);
                    acc[i][3] = fmaf(xs, wv.w, acc[i][3]);
                }
            }
        }
    }

    const int colbase = cb * 64 + cg * 4;
    #pragma unroll
    for (int i = 0; i < 4; ++i) {
        int gr = row0 + rg * 4 + i;
        if (gr < n) {
            float4 o = make_float4(acc[i][0], acc[i][1], acc[i][2], acc[i][3]);
            *(float4*)&H[(size_t)gr * 128 + colbase] = o;
        }
    }
}

// ---- aggregation: one wave per node, edge loop unrolled x4 for MLP --------
__global__ __launch_bounds__(256) void k_aggregate(const float* __restrict__ H,
                                                   const int* __restrict__ rs,
                                                   const int2* __restrict__ ep,
                                                   const float* __restrict__ dinv,
                                                   float* __restrict__ AGG, int n) {
    int wid  = (blockIdx.x * 256 + threadIdx.x) >> 6;   // one wave per node
    int lane = threadIdx.x & 63;
    if (wid >= n) return;
    float sn = dinv[wid]; sn = sn * sn;
    float2 acc = ((const float2*)(H + (size_t)wid * 128))[lane];
    acc.x *= sn; acc.y *= sn;
    int i  = rs[wid];
    int i1 = rs[wid + 1];
    for (; i + 4 <= i1; i += 4) {
        int2 p0 = ep[i + 0];
        int2 p1 = ep[i + 1];
        int2 p2 = ep[i + 2];
        int2 p3 = ep[i + 3];
        float2 v0 = ((const float2*)(H + (size_t)p0.x * 128))[lane];
        float2 v1 = ((const float2*)(H + (size_t)p1.x * 128))[lane];
        float2 v2 = ((const float2*)(H + (size_t)p2.x * 128))[lane];
        float2 v3 = ((const float2*)(H + (size_t)p3.x * 128))[lane];
        float w0 = __int_as_float(p0.y), w1 = __int_as_float(p1.y);
        float w2 = __int_as_float(p2.y), w3 = __int_as_float(p3.y);
        acc.x = fmaf(w0, v0.x, acc.x); acc.y = fmaf(w0, v0.y, acc.y);
        acc.x = fmaf(w1, v1.x, acc.x); acc.y = fmaf(w1, v1.y, acc.y);
        acc.x = fmaf(w2, v2.x, acc.x); acc.y = fmaf(w2, v2.y, acc.y);
        acc.x = fmaf(w3, v3.x, acc.x); acc.y = fmaf(w3, v3.y, acc.y);
    }
    for (; i < i1; ++i) {
        int2 p = ep[i];
        float2 v = ((const float2*)(H + (size_t)p.x * 128))[lane];
        float w = __int_as_float(p.y);
        acc.x = fmaf(w, v.x, acc.x);
        acc.y = fmaf(w, v.y, acc.y);
    }
    ((float2*)(AGG + (size_t)wid * 128))[lane] = acc;
}

// ---- final projection: OUT = relu(a*X+b) @ Wf + bf  (128 -> 40) -----------
__global__ __launch_bounds__(256) void k_gemm_out(const float* __restrict__ X,
                                                  const float* __restrict__ Wf,
                                                  const float* __restrict__ bfv,
                                                  const float* __restrict__ a,
                                                  const float* __restrict__ b,
                                                  float* __restrict__ OUT, int n) {
    __shared__ float xl[32 * 132];    // 16.9 KB
    __shared__ float wt[40 * 132];    // 21.1 KB, transposed Wf: wt[j][c]
    const int tid = threadIdx.x;

    for (int i = tid; i < 128 * 40; i += 256) {
        int c = i / 40;
        int j = i - c * 40;
        wt[j * 132 + c] = Wf[i];
    }
    const int row0 = blockIdx.x * 32;
    for (int i = tid; i < 32 * 32; i += 256) {
        int r = i >> 5, c4 = i & 31;
        int gr = row0 + r;
        float4 v = make_float4(0.f, 0.f, 0.f, 0.f);
        if (gr < n) v = ((const float4*)(X + (size_t)gr * 128))[c4];
        float4 a4 = ((const float4*)a)[c4];
        float4 b4 = ((const float4*)b)[c4];
        v.x = fmaxf(fmaf(v.x, a4.x, b4.x), 0.f);
        v.y = fmaxf(fmaf(v.y, a4.y, b4.y), 0.f);
        v.z = fmaxf(fmaf(v.z, a4.z, b4.z), 0.f);
        v.w = fmaxf(fmaf(v.w, a4.w, b4.w), 0.f);
        *(float4*)&xl[r * 132 + (c4 << 2)] = v;
    }
    __syncthreads();

    const int rg = tid >> 3;   // 32 rows
    const int cg = tid & 7;    // 8 groups x 5 cols
    const int j0 = cg * 5;
    float acc[5] = {0.f, 0.f, 0.f, 0.f, 0.f};
    for (int c = 0; c < 128; c += 4) {
        float4 xv = *(const float4*)&xl[rg * 132 + c];
        #pragma unroll
        for (int j = 0; j < 5; ++j) {
            float4 wv = *(const float4*)&wt[(j0 + j) * 132 + c];
            acc[j] = fmaf(xv.x, wv.x, acc[j]);
            acc[j] = fmaf(xv.y, wv.y, acc[j]);
            acc[j] = fmaf(xv.z, wv.z, acc[j]);
            acc[j] = fmaf(xv.w, wv.w, acc[j]);
        }
    }
    int gr = row0 + rg;
    if (gr < n) {
        #pragma unroll
        for (int j = 0; j < 5; ++j)
            OUT[(size_t)gr * 40 + j0 + j] = acc[j] + bfv[j0 + j];
    }
}

// ---------------------------------------------------------------------------
extern "C" void kernel_launch(void* const* d_in, const int* in_sizes, int n_in,
                              void* d_out, int out_size, void* d_ws, size_t ws_size,
                              hipStream_t stream) {
    const float* X0      = (const float*)d_in[0];
    const int*   edgesrc = (const int*)d_in[1];
    const int*   edgedst = (const int*)d_in[2];
    const float* bn0g = (const float*)d_in[3];
    const float* bn0b = (const float*)d_in[4];
    const float* W1   = (const float*)d_in[5];
    // d_in[6] = b1: cancels in BN1
    const float* bn1g = (const float*)d_in[7];
    const float* bn1b = (const float*)d_in[8];
    const float* W2   = (const float*)d_in[9];
    // d_in[10] = b2: cancels in BN2
    const float* bn2g = (const float*)d_in[11];
    const float* bn2b = (const float*)d_in[12];
    const float* Wf   = (const float*)d_in[13];
    const float* bfv  = (const float*)d_in[14];

    const int n = in_sizes[0] / 128;
    const int e = in_sizes[1];
    float* OUT = (float*)d_out;

    // workspace layout
    float* H     = (float*)d_ws;                 // n*128
    float* AGG   = H + (size_t)n * 128;          // n*128
    float* dinv  = AGG + (size_t)n * 128;        // n
    int2*  ep    = (int2*)(dinv + n);            // e (packed src,norm)
    int*   cnt   = (int*)(ep + e);               // n
    int*   rs    = cnt + n;                      // n+1
    int*   cursor= rs + n + 1;                   // n
    int*   bsum  = cursor + n;                   // 64
    float* stats = (float*)(bsum + 64);          // 3*256 floats
    int*   done  = (int*)(stats + 768);          // 3 counters
    float* a0 = (float*)(done + 4); float* b0 = a0 + 128;
    float* a1 = b0 + 128;           float* b1 = a1 + 128;
    float* a2 = b1 + 128;           float* b2 = a2 + 128;

    hipMemsetAsync(cnt,    0, (size_t)n * sizeof(int), stream);
    hipMemsetAsync(cursor, 0, (size_t)n * sizeof(int), stream);
    hipMemsetAsync(stats,  0, 768 * sizeof(float) + 4 * sizeof(int), stream);

    const float invn = 1.f / (float)n;
    const int nb = (n + 1023) / 1024;

    // CSR build
    k_count<<<(e + 255) / 256, 256, 0, stream>>>(edgedst, e, cnt);
    k_scanA<<<nb, 1024, 0, stream>>>(cnt, n, rs, bsum);
    k_scanC<<<(n + 255) / 256, 256, 0, stream>>>(rs, bsum, cnt, dinv, n, e);
    k_fill<<<(e + 255) / 256, 256, 0, stream>>>(edgesrc, edgedst, e, rs, cursor,
                                                dinv, ep);

    dim3 g1((n + 63) / 64, 2);
    int aggBlocks = (int)(((size_t)n * 64 + 255) / 256);

    // layer 1
    k_colstats<<<256, 256, 0, stream>>>(X0, n, stats, done, bn0g, bn0b, invn,
                                        a0, b0, 256);
    k_gemm128<<<g1, 256, 0, stream>>>(X0, W1, a0, b0, 0, H, n);
    k_aggregate<<<aggBlocks, 256, 0, stream>>>(H, rs, ep, dinv, AGG, n);

    // layer 2
    k_colstats<<<256, 256, 0, stream>>>(AGG, n, stats + 256, done + 1, bn1g, bn1b,
                                        invn, a1, b1, 256);
    k_gemm128<<<g1, 256, 0, stream>>>(AGG, W2, a1, b1, 1, H, n);
    k_aggregate<<<aggBlocks, 256, 0, stream>>>(H, rs, ep, dinv, AGG, n);

    // head
    k_colstats<<<256, 256, 0, stream>>>(AGG, n, stats + 512, done + 2, bn2g, bn2b,
                                        invn, a2, b2, 256);
    k_gemm_out<<<(n + 31) / 32, 256, 0, stream>>>(AGG, Wf, bfv, a2, b2, OUT, n);
}